// Round 11
// baseline (156.516 us; speedup 1.0000x reference)
//
#include <hip/hip_runtime.h>
#include <hip/hip_bf16.h>
#include <stdint.h>

#define N    8192
#define D    256
#define NCLS 100

static constexpr float TEMP    = 0.5f;
static constexpr float SCALE_F = 1.69864360f;  // sqrt(log2e/TEMP)
static constexpr float E2      = 7.38905609893065f;
static constexpr float LN2     = 0.69314718055994531f;

typedef float f32x4 __attribute__((ext_vector_type(4)));
typedef int   i32x8 __attribute__((ext_vector_type(8)));  // 32 B fp8 frag

__device__ __forceinline__ unsigned short f2bf(float f) {
  union { float f; unsigned int u; } x; x.f = f;
  unsigned int r = x.u + 0x7fffu + ((x.u >> 16) & 1u);
  return (unsigned short)(r >> 16);
}
__device__ __forceinline__ float bf2f(unsigned short b) {
  union { unsigned int u; float f; } x; x.u = ((unsigned int)b) << 16;
  return x.f;
}
__device__ __forceinline__ void gld16(const void* g, void* l) {
  __builtin_amdgcn_global_load_lds(
      (const __attribute__((address_space(1))) unsigned int*)g,
      (__attribute__((address_space(3))) unsigned int*)l, 16, 0, 0);
}

// fp8 fragment-major layout, 32-byte k-groups (MX 16x16x128 operand shape):
//   addr(r, k) = (r>>4)*4096 + (k>>5)*512 + (r&15)*32 + (k&31)
// -> each (panel, quad) operand read is one contiguous 512 B segment
//    (lane-linear, 0 bank conflicts); staging is a flat contiguous copy.

// ---- Kernel A: row-normalize; bf16 row-major copy (class sums) + fp8 e4m3
// fragment-major copy (GEMM); zeroes rowsum.
__global__ __launch_bounds__(256) void normalize_kernel(
    const float* __restrict__ emb, const long long* __restrict__ label,
    unsigned short* __restrict__ abf, unsigned char* __restrict__ a8,
    float* __restrict__ rowsum, int* __restrict__ cnt,
    int* __restrict__ list) {
  const int row  = blockIdx.x * 4 + (threadIdx.x >> 6);
  const int lane = threadIdx.x & 63;
  const float4 v = ((const float4*)(emb + (size_t)row * D))[lane];
  float ss = v.x * v.x + v.y * v.y + v.z * v.z + v.w * v.w;
#pragma unroll
  for (int off = 1; off < 64; off <<= 1) ss += __shfl_xor(ss, off);
  const float s = rsqrtf(ss) * SCALE_F;
  const float x = v.x * s, y = v.y * s, z = v.z * s, wv = v.w * s;

  ushort4 o;
  o.x = f2bf(x); o.y = f2bf(y); o.z = f2bf(z); o.w = f2bf(wv);
  ((ushort4*)(abf + (size_t)row * D))[lane] = o;

  int p = __builtin_amdgcn_cvt_pk_fp8_f32(x, y, 0, false);
  p = __builtin_amdgcn_cvt_pk_fp8_f32(z, wv, p, true);
  // k = lane*4 .. +3 -> 32B-group = lane>>3, word-in-group = lane&7
  *(int*)(a8 + (size_t)(row >> 4) * 4096 + (lane >> 3) * 512 +
          (row & 15) * 32 + (lane & 7) * 4) = p;

  if (lane == 0) {
    rowsum[row] = 0.f;
    const int c = (int)label[row];
    const int slot = atomicAdd(cnt + c, 1);
    list[c * 256 + slot] = row;
  }
}

// ---- Kernel B: A-tile resident in LDS (full K); B in half-K double buffers.
// MX-scaled fp8 MFMA (K=128/instr, unit E8M0 scales = exact fp8 math):
// 4x fewer MFMA instructions than 16x16x32 fp8 at 2x the FLOP rate.
#define TM 128
#define TN 128
#define JT 4

__global__ __launch_bounds__(256) void simexp_rowsum_kernel(
    const unsigned char* __restrict__ A, float* __restrict__ rowsum) {
  __shared__ __align__(32) unsigned char sa[TM * 256];     // 32 KB, full K
  __shared__ __align__(32) unsigned char sb[2][TN * 128];  // 2 x 16 KB halves
  const int tid  = threadIdx.x;
  const int w    = tid >> 6;
  const int lane = tid & 63;
  const int quad = lane >> 4;
  const int l15  = lane & 15;
  const int row0 = blockIdx.y * TM;
  const int jc0  = blockIdx.x * (TN * JT);
  const int pr0  = row0 >> 4;      // first 16-row panel of A-tile
  const int pam  = (w & 1) * 4;    // wave's A panel base (local)
  const int pbn  = (w >> 1) * 4;   // wave's B panel base (local)
  const int wm   = (w & 1) * 64;

  // Stage full A-tile: 32 segs of 1024 B; wave w stages segs w*8..w*8+7.
#pragma unroll
  for (int p = 0; p < 8; ++p) {
    const int seg = w * 8 + p;  // wave-uniform
    gld16(A + (size_t)(pr0 + (seg >> 2)) * 4096 + (seg & 3) * 1024 + lane * 16,
          sa + seg * 1024);
  }
  // Stage B(jt=0, kc=0) into buffer 0.
#pragma unroll
  for (int p = 0; p < 4; ++p) {
    const int seg = w * 4 + p;
    gld16(A + (size_t)((jc0 >> 4) + (seg >> 1)) * 4096 + (seg & 1) * 1024 +
              lane * 16,
          sb[0] + seg * 1024);
  }
  __syncthreads();

  float rowpart[4][4];
#pragma unroll
  for (int mt = 0; mt < 4; ++mt)
#pragma unroll
    for (int e = 0; e < 4; ++e) rowpart[mt][e] = 0.f;

  int buf = 0;
  for (int jt = 0; jt < JT; ++jt) {
    f32x4 acc[4][4];
#pragma unroll
    for (int mt = 0; mt < 4; ++mt)
#pragma unroll
      for (int nt = 0; nt < 4; ++nt) acc[mt][nt] = (f32x4){0.f, 0.f, 0.f, 0.f};

#pragma unroll
    for (int kc = 0; kc < 2; ++kc) {
      // Prefetch the next half-K B chunk into the other buffer.
      if (!(jt == JT - 1 && kc == 1)) {
        const int njt = (kc == 1) ? jt + 1 : jt;
        const int nkc = kc ^ 1;
        const int pj0 = (jc0 + njt * TN) >> 4;
#pragma unroll
        for (int p = 0; p < 4; ++p) {
          const int seg = w * 4 + p;
          gld16(A + (size_t)(pj0 + (seg >> 1)) * 4096 + nkc * 2048 +
                    (seg & 1) * 1024 + lane * 16,
                sb[buf ^ 1] + seg * 1024);
        }
      }
      // Compute: one K=128 MX MFMA per (mt,nt). Operand frag: quad q owns
      // k-group q -> contiguous 512 B segment, lane-linear (0 conflicts).
      {
        const int fo = quad * 512 + l15 * 32;
        i32x8 af[4], bf[4];
#pragma unroll
        for (int mt = 0; mt < 4; ++mt)
          af[mt] = *(const i32x8*)(sa + (pam + mt) * 4096 + kc * 2048 + fo);
#pragma unroll
        for (int nt = 0; nt < 4; ++nt)
          bf[nt] = *(const i32x8*)(sb[buf] + (pbn + nt) * 2048 + fo);
#pragma unroll
        for (int mt = 0; mt < 4; ++mt)
#pragma unroll
          for (int nt = 0; nt < 4; ++nt)
            acc[mt][nt] = __builtin_amdgcn_mfma_scale_f32_16x16x128_f8f6f4(
                af[mt], bf[nt], acc[mt][nt],
                0, 0,          // cbsz=0 (A fp8 e4m3), blgp=0 (B fp8 e4m3)
                0, 127,        // A scale: opsel 0, E8M0 127 = 2^0
                0, 127);       // B scale: opsel 0, E8M0 127 = 2^0
      }
      __syncthreads();
      buf ^= 1;
    }

    // epilogue: exp2 of every sim element, accumulate row partials
#pragma unroll
    for (int mt = 0; mt < 4; ++mt)
#pragma unroll
      for (int nt = 0; nt < 4; ++nt)
#pragma unroll
        for (int e = 0; e < 4; ++e)
          rowpart[mt][e] += __builtin_amdgcn_exp2f(acc[mt][nt][e]);
  }

  // C layout: col = l15, row-in-16 = quad*4 + e. Reduce over 16 cols, one
  // atomic per row per block.
#pragma unroll
  for (int mt = 0; mt < 4; ++mt)
#pragma unroll
    for (int e = 0; e < 4; ++e) {
      float v = rowpart[mt][e];
      v += __shfl_xor(v, 1);
      v += __shfl_xor(v, 2);
      v += __shfl_xor(v, 4);
      v += __shfl_xor(v, 8);
      if (l15 == 0)
        atomicAdd(&rowsum[row0 + wm + mt * 16 + quad * 4 + e], v);
    }
}

__global__ __launch_bounds__(256) void finalize_kernel(
    const unsigned short* __restrict__ abf, const float* __restrict__ rowsum,
    const long long* __restrict__ label, const int* __restrict__ cnt,
    const int* __restrict__ list, float* __restrict__ out) {
  __shared__ float red[4];
  __shared__ int rows_l[256];
  const int tid  = threadIdx.x;
  const int w    = tid >> 6;
  const int lane = tid & 63;

  if (blockIdx.x < NCLS) {
    const int c = blockIdx.x;
    const int m = cnt[c];
    if (m <= 1) return;
    if (tid < m) rows_l[tid] = list[c * 256 + tid];
    __syncthreads();
    float acc = 0.f;
    for (int s = 0; s < m; ++s)
      acc += bf2f(abf[(size_t)rows_l[s] * D + tid]);
    float v = acc * acc;
#pragma unroll
    for (int off = 1; off < 64; off <<= 1) v += __shfl_xor(v, off);
    if (lane == 0) red[w] = v;
    __syncthreads();
    if (tid == 0) {
      const float ssq = red[0] + red[1] + red[2] + red[3];
      const float term = (ssq * LN2 - 2.0f * (float)m) / (float)(m - 1);
      atomicAdd(out, -term);
    }
  } else {
    const int i = (blockIdx.x - NCLS) * 256 + tid;
    const int c = (int)label[i];
    float v = 0.f;
    if (cnt[c] > 1)
      v = __builtin_amdgcn_logf(rowsum[i] - E2) * LN2;
#pragma unroll
    for (int off = 1; off < 64; off <<= 1) v += __shfl_xor(v, off);
    if (lane == 0) red[w] = v;
    __syncthreads();
    if (tid == 0)
      atomicAdd(out, red[0] + red[1] + red[2] + red[3]);
  }
}

extern "C" void kernel_launch(void* const* d_in, const int* in_sizes, int n_in,
                              void* d_out, int out_size, void* d_ws,
                              size_t ws_size, hipStream_t stream) {
  const float* emb = (const float*)d_in[0];
  const long long* label = (const long long*)d_in[1];
  float* out = (float*)d_out;

  char* ws = (char*)d_ws;
  unsigned short* abf = (unsigned short*)ws;            // 4 MB bf16 row-major
  unsigned char* a8 = (unsigned char*)(ws + (size_t)N * D * 2);  // 2 MB fp8
  float* rowsum = (float*)(ws + (size_t)N * D * 3);     // N floats
  int* cnt = (int*)(rowsum + N);                        // 128 ints
  int* list = cnt + 128;                                // NCLS*256 ints

  hipMemsetAsync(cnt, 0, 128 * 4, stream);
  hipMemsetAsync(out, 0, sizeof(float), stream);

  normalize_kernel<<<N / 4, 256, 0, stream>>>(emb, label, abf, a8, rowsum,
                                              cnt, list);

  dim3 gridB(N / (TN * JT), N / TM);  // (16, 64) -> 1024 blocks
  simexp_rowsum_kernel<<<gridB, 256, 0, stream>>>(a8, rowsum);

  finalize_kernel<<<NCLS + N / 256, 256, 0, stream>>>(abf, rowsum, label, cnt,
                                                      list, out);
}

// Round 12
// 132.757 us; speedup vs baseline: 1.1790x; 1.1790x over previous
//
#include <hip/hip_runtime.h>
#include <hip/hip_bf16.h>
#include <stdint.h>

#define N    8192
#define D    256
#define NCLS 100

static constexpr float TEMP    = 0.5f;
static constexpr float SCALE_F = 1.69864360f;  // sqrt(log2e/TEMP)
static constexpr float E2      = 7.38905609893065f;
static constexpr float LN2     = 0.69314718055994531f;

typedef float f32x4 __attribute__((ext_vector_type(4)));

__device__ __forceinline__ unsigned short f2bf(float f) {
  union { float f; unsigned int u; } x; x.f = f;
  unsigned int r = x.u + 0x7fffu + ((x.u >> 16) & 1u);
  return (unsigned short)(r >> 16);
}
__device__ __forceinline__ float bf2f(unsigned short b) {
  union { unsigned int u; float f; } x; x.u = ((unsigned int)b) << 16;
  return x.f;
}
__device__ __forceinline__ void gld16(const void* g, void* l) {
  __builtin_amdgcn_global_load_lds(
      (const __attribute__((address_space(1))) unsigned int*)g,
      (__attribute__((address_space(3))) unsigned int*)l, 16, 0, 0);
}

// fp8 fragment-major layout:
//   addr(r, k) = (r>>4)*4096 + (k>>3)*128 + (r&15)*8 + (k&7)
// -> GEMM LDS reads are lane-linear 128B segments (0 bank conflicts);
// -> staging is a flat contiguous copy; K-halves of a panel are contiguous.

// ---- Kernel A: row-normalize; bf16 row-major copy (class sums) + fp8 e4m3
// fragment-major copy (GEMM); also zeroes rowsum (folds the memset).
__global__ __launch_bounds__(256) void normalize_kernel(
    const float* __restrict__ emb, const long long* __restrict__ label,
    unsigned short* __restrict__ abf, unsigned char* __restrict__ a8,
    float* __restrict__ rowsum, int* __restrict__ cnt,
    int* __restrict__ list) {
  const int row  = blockIdx.x * 4 + (threadIdx.x >> 6);
  const int lane = threadIdx.x & 63;
  const float4 v = ((const float4*)(emb + (size_t)row * D))[lane];
  float ss = v.x * v.x + v.y * v.y + v.z * v.z + v.w * v.w;
#pragma unroll
  for (int off = 1; off < 64; off <<= 1) ss += __shfl_xor(ss, off);
  const float s = rsqrtf(ss) * SCALE_F;
  const float x = v.x * s, y = v.y * s, z = v.z * s, wv = v.w * s;

  ushort4 o;
  o.x = f2bf(x); o.y = f2bf(y); o.z = f2bf(z); o.w = f2bf(wv);
  ((ushort4*)(abf + (size_t)row * D))[lane] = o;

  int p = __builtin_amdgcn_cvt_pk_fp8_f32(x, y, 0, false);
  p = __builtin_amdgcn_cvt_pk_fp8_f32(z, wv, p, true);
  // k = lane*4 .. +3 -> octet = lane>>1, 4B half = lane&1
  *(int*)(a8 + (size_t)(row >> 4) * 4096 + (lane >> 1) * 128 +
          (row & 15) * 8 + (lane & 1) * 4) = p;

  if (lane == 0) {
    rowsum[row] = 0.f;
    const int c = (int)label[row];
    const int slot = atomicAdd(cnt + c, 1);
    list[c * 256 + slot] = row;
  }
}

// ---- Kernel B: A-tile resident in LDS (staged once, full K); B-tile in
// half-K double buffers, prefetched one phase ahead. fp8 e4m3 16x16x32
// MFMA; fragment-major LDS reads are lane-linear (0 bank conflicts).
#define TM 128
#define TN 128
#define JT 4

__global__ __launch_bounds__(256) void simexp_rowsum_kernel(
    const unsigned char* __restrict__ A, float* __restrict__ rowsum) {
  __shared__ __align__(16) unsigned char sa[TM * 256];     // 32 KB, full K
  __shared__ __align__(16) unsigned char sb[2][TN * 128];  // 2 x 16 KB halves
  const int tid  = threadIdx.x;
  const int w    = tid >> 6;
  const int lane = tid & 63;
  const int quad = lane >> 4;
  const int l15  = lane & 15;
  const int row0 = blockIdx.y * TM;
  const int jc0  = blockIdx.x * (TN * JT);
  const int pr0  = row0 >> 4;      // first 16-row panel of A-tile
  const int pam  = (w & 1) * 4;    // wave's A panel base (local)
  const int pbn  = (w >> 1) * 4;   // wave's B panel base (local)
  const int wm   = (w & 1) * 64;

  // Stage full A-tile: 32 segs of 1024 B; wave w stages segs w*8..w*8+7.
#pragma unroll
  for (int p = 0; p < 8; ++p) {
    const int seg = w * 8 + p;  // wave-uniform
    gld16(A + (size_t)(pr0 + (seg >> 2)) * 4096 + (seg & 3) * 1024 + lane * 16,
          sa + seg * 1024);
  }
  // Stage B(jt=0, kc=0) into buffer 0.
#pragma unroll
  for (int p = 0; p < 4; ++p) {
    const int seg = w * 4 + p;
    gld16(A + (size_t)((jc0 >> 4) + (seg >> 1)) * 4096 + (seg & 1) * 1024 +
              lane * 16,
          sb[0] + seg * 1024);
  }
  __syncthreads();

  float rowpart[4][4];
#pragma unroll
  for (int mt = 0; mt < 4; ++mt)
#pragma unroll
    for (int e = 0; e < 4; ++e) rowpart[mt][e] = 0.f;

  int buf = 0;
  for (int jt = 0; jt < JT; ++jt) {
    f32x4 acc[4][4];
#pragma unroll
    for (int mt = 0; mt < 4; ++mt)
#pragma unroll
      for (int nt = 0; nt < 4; ++nt) acc[mt][nt] = (f32x4){0.f, 0.f, 0.f, 0.f};

#pragma unroll
    for (int kc = 0; kc < 2; ++kc) {
      // Prefetch the next half-K B chunk into the other buffer.
      if (!(jt == JT - 1 && kc == 1)) {
        const int njt = (kc == 1) ? jt + 1 : jt;
        const int nkc = kc ^ 1;
        const int pj0 = (jc0 + njt * TN) >> 4;
#pragma unroll
        for (int p = 0; p < 4; ++p) {
          const int seg = w * 4 + p;
          gld16(A + (size_t)(pj0 + (seg >> 1)) * 4096 + nkc * 2048 +
                    (seg & 1) * 1024 + lane * 16,
                sb[buf ^ 1] + seg * 1024);
        }
      }
      // Compute from sb[buf] against the kc-half of resident A.
#pragma unroll
      for (int kk = 0; kk < 4; ++kk) {
        const int fo = (kk * 4 + quad) * 128 + l15 * 8;  // lane-linear
        long af[4], bf[4];
#pragma unroll
        for (int mt = 0; mt < 4; ++mt)
          af[mt] = *(const long*)(sa + (pam + mt) * 4096 + kc * 2048 + fo);
#pragma unroll
        for (int nt = 0; nt < 4; ++nt)
          bf[nt] = *(const long*)(sb[buf] + (pbn + nt) * 2048 + fo);
#pragma unroll
        for (int mt = 0; mt < 4; ++mt)
#pragma unroll
          for (int nt = 0; nt < 4; ++nt)
            acc[mt][nt] = __builtin_amdgcn_mfma_f32_16x16x32_fp8_fp8(
                af[mt], bf[nt], acc[mt][nt], 0, 0, 0);
      }
      __syncthreads();
      buf ^= 1;
    }

    // epilogue: exp2 of every sim element, accumulate row partials
#pragma unroll
    for (int mt = 0; mt < 4; ++mt)
#pragma unroll
      for (int nt = 0; nt < 4; ++nt)
#pragma unroll
        for (int e = 0; e < 4; ++e)
          rowpart[mt][e] += __builtin_amdgcn_exp2f(acc[mt][nt][e]);
  }

  // C layout: col = l15, row-in-16 = quad*4 + e. Reduce over 16 cols, one
  // atomic per row per block.
#pragma unroll
  for (int mt = 0; mt < 4; ++mt)
#pragma unroll
    for (int e = 0; e < 4; ++e) {
      float v = rowpart[mt][e];
      v += __shfl_xor(v, 1);
      v += __shfl_xor(v, 2);
      v += __shfl_xor(v, 4);
      v += __shfl_xor(v, 8);
      if (l15 == 0)
        atomicAdd(&rowsum[row0 + wm + mt * 16 + quad * 4 + e], v);
    }
}

__global__ __launch_bounds__(256) void finalize_kernel(
    const unsigned short* __restrict__ abf, const float* __restrict__ rowsum,
    const long long* __restrict__ label, const int* __restrict__ cnt,
    const int* __restrict__ list, float* __restrict__ out) {
  __shared__ float red[4];
  __shared__ int rows_l[256];
  const int tid  = threadIdx.x;
  const int w    = tid >> 6;
  const int lane = tid & 63;

  if (blockIdx.x < NCLS) {
    const int c = blockIdx.x;
    const int m = cnt[c];
    if (m <= 1) return;
    if (tid < m) rows_l[tid] = list[c * 256 + tid];
    __syncthreads();
    float acc = 0.f;
    for (int s = 0; s < m; ++s)
      acc += bf2f(abf[(size_t)rows_l[s] * D + tid]);
    float v = acc * acc;
#pragma unroll
    for (int off = 1; off < 64; off <<= 1) v += __shfl_xor(v, off);
    if (lane == 0) red[w] = v;
    __syncthreads();
    if (tid == 0) {
      const float ssq = red[0] + red[1] + red[2] + red[3];
      const float term = (ssq * LN2 - 2.0f * (float)m) / (float)(m - 1);
      atomicAdd(out, -term);
    }
  } else {
    const int i = (blockIdx.x - NCLS) * 256 + tid;
    const int c = (int)label[i];
    float v = 0.f;
    if (cnt[c] > 1)
      v = __builtin_amdgcn_logf(rowsum[i] - E2) * LN2;
#pragma unroll
    for (int off = 1; off < 64; off <<= 1) v += __shfl_xor(v, off);
    if (lane == 0) red[w] = v;
    __syncthreads();
    if (tid == 0)
      atomicAdd(out, red[0] + red[1] + red[2] + red[3]);
  }
}

extern "C" void kernel_launch(void* const* d_in, const int* in_sizes, int n_in,
                              void* d_out, int out_size, void* d_ws,
                              size_t ws_size, hipStream_t stream) {
  const float* emb = (const float*)d_in[0];
  const long long* label = (const long long*)d_in[1];
  float* out = (float*)d_out;

  char* ws = (char*)d_ws;
  unsigned short* abf = (unsigned short*)ws;            // 4 MB bf16 row-major
  unsigned char* a8 = (unsigned char*)(ws + (size_t)N * D * 2);  // 2 MB fp8
  float* rowsum = (float*)(ws + (size_t)N * D * 3);     // N floats
  int* cnt = (int*)(rowsum + N);                        // 128 ints
  int* list = cnt + 128;                                // NCLS*256 ints

  hipMemsetAsync(cnt, 0, 128 * 4, stream);
  hipMemsetAsync(out, 0, sizeof(float), stream);

  normalize_kernel<<<N / 4, 256, 0, stream>>>(emb, label, abf, a8, rowsum,
                                              cnt, list);

  dim3 gridB(N / (TN * JT), N / TM);  // (16, 64) -> 1024 blocks
  simexp_rowsum_kernel<<<gridB, 256, 0, stream>>>(a8, rowsum);

  finalize_kernel<<<NCLS + N / 256, 256, 0, stream>>>(abf, rowsum, label, cnt,
                                                      list, out);
}